// Round 1
// baseline (141.852 us; speedup 1.0000x reference)
//
#include <hip/hip_runtime.h>
#include <math.h>

// Problem constants
constexpr int B_   = 32;
constexpr int G_   = 8;
constexpr int CIN  = 64;
constexpr int CAPS = 4;
constexpr int OUT  = 64;
constexpr int HID  = 512;           // CIN * RATIO
constexpr int CO   = CAPS * OUT;    // 256
constexpr int HW   = 64 * 64;       // 4096

// ---------------------------------------------------------------------------
// Kernel A: pooled[ch] = mean over HW of embedding[ch*HW + j],  ch in [0, B*G*CIN)
// ---------------------------------------------------------------------------
__global__ __launch_bounds__(256) void pool_kernel(const float* __restrict__ emb,
                                                   float* __restrict__ pooled) {
    const int ch = blockIdx.x;
    const float4* p = reinterpret_cast<const float4*>(emb + (size_t)ch * HW);
    float s = 0.f;
    for (int i = threadIdx.x; i < HW / 4; i += 256) {
        float4 v = p[i];
        s += v.x + v.y + v.z + v.w;
    }
    // wave (64-lane) reduce
    for (int off = 32; off; off >>= 1) s += __shfl_down(s, off);
    __shared__ float ws[4];
    const int lane = threadIdx.x & 63, wid = threadIdx.x >> 6;
    if (lane == 0) ws[wid] = s;
    __syncthreads();
    if (threadIdx.x == 0) {
        float t = ws[0] + ws[1] + ws[2] + ws[3];
        pooled[ch] = t * (1.0f / HW);
    }
}

// ---------------------------------------------------------------------------
// Kernel B: per (b,g): h = relu(pooled @ w1^T + b1); atts = h @ w2^T + b2
// w1: [G, HID, CIN]  w2: [G, CO, HID]
// ---------------------------------------------------------------------------
__global__ __launch_bounds__(256) void fc_kernel(const float* __restrict__ pooled,
                                                 const float* __restrict__ w1,
                                                 const float* __restrict__ b1,
                                                 const float* __restrict__ w2,
                                                 const float* __restrict__ b2,
                                                 float* __restrict__ atts) {
    const int bg = blockIdx.x;
    const int b = bg / G_, g = bg % G_;
    __shared__ float pin[CIN];
    __shared__ float h[HID];
    const int t = threadIdx.x;
    if (t < CIN) pin[t] = pooled[(size_t)(b * G_ + g) * CIN + t];
    __syncthreads();

    const float* W1 = w1 + (size_t)g * HID * CIN;
    for (int o = t; o < HID; o += 256) {
        const float4* wrow = reinterpret_cast<const float4*>(W1 + (size_t)o * CIN);
        float acc = b1[g * HID + o];
        #pragma unroll
        for (int i = 0; i < CIN / 4; ++i) {
            float4 w = wrow[i];
            acc += w.x * pin[4 * i] + w.y * pin[4 * i + 1] +
                   w.z * pin[4 * i + 2] + w.w * pin[4 * i + 3];
        }
        h[o] = fmaxf(acc, 0.f);
    }
    __syncthreads();

    const float* W2 = w2 + (size_t)g * CO * HID;
    {
        const int o = t;  // 256 threads == CO outputs
        const float4* wrow = reinterpret_cast<const float4*>(W2 + (size_t)o * HID);
        float acc = b2[g * CO + o];
        #pragma unroll 8
        for (int i = 0; i < HID / 4; ++i) {
            float4 w = wrow[i];
            acc += w.x * h[4 * i] + w.y * h[4 * i + 1] +
                   w.z * h[4 * i + 2] + w.w * h[4 * i + 3];
        }
        atts[(size_t)(b * G_ + g) * CO + o] = acc;
    }
}

// ---------------------------------------------------------------------------
// Kernel C: dynamic routing per batch; writes matt[b][CO] = sigmoid(routed)
// ---------------------------------------------------------------------------
__global__ __launch_bounds__(256) void routing_kernel(const float* __restrict__ atts,
                                                      float* __restrict__ matt) {
    const int b = blockIdx.x;
    __shared__ float xr[G_ * CAPS * OUT];   // 2048 floats
    __shared__ float beta[G_ * CAPS];
    __shared__ float alpha[G_ * CAPS];
    __shared__ float v[CAPS * OUT];         // 256
    __shared__ float nrm[CAPS];
    const int t = threadIdx.x;
    for (int i = t; i < G_ * CAPS * OUT; i += 256)
        xr[i] = atts[(size_t)b * G_ * CO + i];
    if (t < G_ * CAPS) beta[t] = 0.f;
    __syncthreads();

    for (int iter = 0; iter < 3; ++iter) {
        // softmax over caps (axis=2), per (g)
        if (t < G_ * CAPS) {
            const int g = t / CAPS;
            float m = fmaxf(fmaxf(beta[g * CAPS + 0], beta[g * CAPS + 1]),
                            fmaxf(beta[g * CAPS + 2], beta[g * CAPS + 3]));
            float se = 0.f;
            #pragma unroll
            for (int c = 0; c < CAPS; ++c) se += expf(beta[g * CAPS + c] - m);
            alpha[t] = expf(beta[t] - m) / se;
        }
        __syncthreads();
        // v[c][o] = sum_g alpha[g][c] * xr[g][c][o]
        {
            const int c = t >> 6, o = t & 63;
            float acc = 0.f;
            #pragma unroll
            for (int g = 0; g < G_; ++g)
                acc += alpha[g * CAPS + c] * xr[(g * CAPS + c) * OUT + o];
            v[t] = acc;
        }
        __syncthreads();
        if (iter == 2) {
            matt[(size_t)b * CO + t] = 1.f / (1.f + expf(-v[t]));
        } else {
            // nrm[c] = sqrt(sum_o v[c][o]^2); wave w (= c) reduces its 64 elems
            float sq = v[t] * v[t];
            for (int off = 32; off; off >>= 1) sq += __shfl_down(sq, off);
            if ((t & 63) == 0) nrm[t >> 6] = sqrtf(sq);
            __syncthreads();
            // beta[g][c] += sum_o (v[c][o]/max(nrm[c],1e-12)) * xr[g][c][o]
            if (t < G_ * CAPS) {
                const int g = t / CAPS, c = t % CAPS;
                const float inv = 1.f / fmaxf(nrm[c], 1e-12f);
                float acc = 0.f;
                #pragma unroll
                for (int o = 0; o < OUT; ++o)
                    acc += v[c * OUT + o] * xr[(g * CAPS + c) * OUT + o];
                beta[t] += acc * inv;
            }
            __syncthreads();
        }
    }
}

// ---------------------------------------------------------------------------
// Kernel D: out[b,c,:,:] = matt[b,c] * x[b,c,:,:]   (float4 grid-stride)
// ---------------------------------------------------------------------------
__global__ __launch_bounds__(256) void scale_kernel(const float* __restrict__ x,
                                                    const float* __restrict__ matt,
                                                    float* __restrict__ out,
                                                    int total4) {
    const int stride = gridDim.x * blockDim.x;
    const float4* xi = reinterpret_cast<const float4*>(x);
    float4* oi = reinterpret_cast<float4*>(out);
    for (int i = blockIdx.x * blockDim.x + threadIdx.x; i < total4; i += stride) {
        const int ch = i >> 10;          // 1024 float4 per channel; ch = b*CO + c
        const float s = matt[ch];
        float4 v = xi[i];
        v.x *= s; v.y *= s; v.z *= s; v.w *= s;
        oi[i] = v;
    }
}

extern "C" void kernel_launch(void* const* d_in, const int* in_sizes, int n_in,
                              void* d_out, int out_size, void* d_ws, size_t ws_size,
                              hipStream_t stream) {
    const float* emb = (const float*)d_in[0];
    const float* x   = (const float*)d_in[1];
    const float* w1  = (const float*)d_in[2];
    const float* b1  = (const float*)d_in[3];
    const float* w2  = (const float*)d_in[4];
    const float* b2  = (const float*)d_in[5];
    float* out = (float*)d_out;

    // workspace layout (floats)
    float* ws     = (float*)d_ws;
    float* pooled = ws;                       // B*G*CIN   = 16384
    float* atts   = ws + 16384;               // B*G*CO    = 65536
    float* matt   = ws + 16384 + 65536;       // B*CO      = 8192

    pool_kernel<<<B_ * G_ * CIN, 256, 0, stream>>>(emb, pooled);
    fc_kernel<<<B_ * G_, 256, 0, stream>>>(pooled, w1, b1, w2, b2, atts);
    routing_kernel<<<B_, 256, 0, stream>>>(atts, matt);
    const int total4 = B_ * CO * (HW / 4);    // 8,388,608
    scale_kernel<<<2048, 256, 0, stream>>>(x, matt, out, total4);
}